// Round 6
// baseline (720.061 us; speedup 1.0000x reference)
//
#include <hip/hip_runtime.h>

// AliNetGraphAttentionLayer: N=100000, E=1600000, D_IN=256, D_OUT=128
// R13: quadmap at 512 threads / 8 waves (2Mx4N wave grid), same 80KB LDS
// -> 16 waves/CU (was 8): latency hiding for LDS reads + MFMA chains.
// Per-output-column MFMA chains bitwise-identical to R12 (mapped exact);
// s1/s2 reduction regrouped (fp32 reorder ~1e-7, invisible vs 0.0156).
// Restored R11 split row_softmax+alpha+gather (R12 fusion was -30us) and
// colstats grid 512.
#define D_IN 256
#define D_OUT 128
#define EPS_BN 1e-3f
#define LEAKY 0.2f

typedef unsigned short u16;
typedef unsigned int u32;
typedef u16 u16x4 __attribute__((ext_vector_type(4)));
typedef u16 u16x8 __attribute__((ext_vector_type(8)));
typedef __bf16 bf16x8 __attribute__((ext_vector_type(8)));
typedef float f32x4 __attribute__((ext_vector_type(4)));

__device__ __forceinline__ float bf2f(u16 u) {
    u32 v = ((u32)u) << 16;
    return __uint_as_float(v);
}
__device__ __forceinline__ u16 f2bf(float f) {
    u32 u = __float_as_uint(f);
    u32 r = (u + 0x7FFFu + ((u >> 16) & 1u)) >> 16;  // RNE
    return (u16)r;
}

// raw barrier with LDS-only drain: global loads stay in flight across it
__device__ __forceinline__ void bar_lgkm() {
    asm volatile("s_waitcnt lgkmcnt(0)" ::: "memory");
    __builtin_amdgcn_s_barrier();
    asm volatile("" ::: "memory");
}

// ---------------- column stats (float4 vectorized) ----------------
__global__ void colstats_k(const float* __restrict__ x, int n,
                           float* __restrict__ sums, float* __restrict__ sqs) {
    int c4 = (threadIdx.x & 63) << 2;
    int rp = threadIdx.x >> 6;
    float s0 = 0.f, s1 = 0.f, s2 = 0.f, s3 = 0.f;
    float q0 = 0.f, q1 = 0.f, q2 = 0.f, q3 = 0.f;
    for (int r = blockIdx.x * 4 + rp; r < n; r += gridDim.x * 4) {
        float4 v = *(const float4*)(x + (size_t)r * D_IN + c4);
        s0 += v.x; q0 += v.x * v.x;
        s1 += v.y; q1 += v.y * v.y;
        s2 += v.z; q2 += v.z * v.z;
        s3 += v.w; q3 += v.w * v.w;
    }
    atomicAdd(&sums[c4 + 0], s0);
    atomicAdd(&sums[c4 + 1], s1);
    atomicAdd(&sums[c4 + 2], s2);
    atomicAdd(&sums[c4 + 3], s3);
    atomicAdd(&sqs[c4 + 0], q0);
    atomicAdd(&sqs[c4 + 1], q1);
    atomicAdd(&sqs[c4 + 2], q2);
    atomicAdd(&sqs[c4 + 3], q3);
}

__global__ void finalize_k(const float* __restrict__ sums, const float* __restrict__ sqs,
                           int n, float* __restrict__ mean, float* __restrict__ inv) {
    int c = threadIdx.x;
    float m = sums[c] / (float)n;
    float v = sqs[c] / (float)n - m * m;
    mean[c] = m;
    inv[c] = rsqrtf(v + EPS_BN);
}

// ---------------- W split prep: Bt[n][k] = W[k][n] as hi/lo bf16 ----------------
__global__ void prep_w_k(const float* __restrict__ w1, const float* __restrict__ w2,
                         const float* __restrict__ w, u16* __restrict__ Bth,
                         u16* __restrict__ Btl, u16* __restrict__ Wth,
                         u16* __restrict__ Wtl) {
    int idx = blockIdx.x * 256 + threadIdx.x;  // 640*256 threads
    int k = idx & 255;
    int nn = idx >> 8;
    if (nn < 512) {
        float v = (nn < 256) ? w1[(size_t)k * 256 + nn]
                             : w2[(size_t)k * 256 + (nn - 256)];
        u16 h = f2bf(v);
        u16 l = f2bf(v - bf2f(h));
        Bth[(size_t)nn * 256 + k] = h;
        Btl[(size_t)nn * 256 + k] = l;
    } else {
        int nm = nn - 512;  // output col 0..127
        float v = w[(size_t)k * D_OUT + nm];
        u16 h = f2bf(v);
        u16 l = f2bf(v - bf2f(h));
        Wth[(size_t)nm * 256 + k] = h;
        Wtl[(size_t)nm * 256 + k] = l;
    }
}

// ---------------- MFMA fragment-layout probe ----------------
__device__ __forceinline__ int kmap(int v, int g, int j) {
    return (v == 0) ? (8 * g + j) : (16 * (j >> 2) + 4 * g + (j & 3));
}

__global__ void probe_k(int* __restrict__ flagp) {
    __shared__ float Ar[16][32];
    __shared__ float Br[32][16];
    __shared__ float Dr[16][16];
    int l = threadIdx.x;  // 64 threads
    for (int i = l; i < 512; i += 64) {
        int r = i >> 5, k = i & 31;
        Ar[r][k] = (float)(((r * 5 + k * 3) % 11) - 5);
    }
    for (int i = l; i < 512; i += 64) {
        int k = i >> 4, c = i & 15;
        Br[k][c] = (float)(((k * 3 + c * 7) % 13) - 6);
    }
    __syncthreads();
    for (int i = l; i < 256; i += 64) {
        int r = i >> 4, c = i & 15;
        float s = 0.f;
        for (int k = 0; k < 32; ++k) s += Ar[r][k] * Br[k][c];
        Dr[r][c] = s;
    }
    __syncthreads();
    int g = l >> 4, c15 = l & 15;
    int found = -1;
    for (int combo = 0; combo < 4; ++combo) {
        int va = combo >> 1, vb = combo & 1;
        u16x8 af, bfv;
#pragma unroll
        for (int j = 0; j < 8; ++j) {
            af[j] = f2bf(Ar[c15][kmap(va, g, j)]);
            bfv[j] = f2bf(Br[kmap(vb, g, j)][c15]);
        }
        f32x4 d = {0.f, 0.f, 0.f, 0.f};
        d = __builtin_amdgcn_mfma_f32_16x16x32_bf16(
            __builtin_bit_cast(bf16x8, af), __builtin_bit_cast(bf16x8, bfv), d,
            0, 0, 0);
        bool ok = true;
#pragma unroll
        for (int r = 0; r < 4; ++r) ok = ok && (d[r] == Dr[g * 4 + r][c15]);
        if (found < 0 && __all(ok)) found = combo;
    }
    if (l == 0) flagp[0] = (found < 0) ? 0 : found;
}

// ---------------- staging helpers ----------------
// A planes: [64 rows][256 k] bf16, row stride 512 B, swizzle byte^=(row&7)<<4
// NT = threads in block
template <int NT>
__device__ __forceinline__ void stage_A(const float* __restrict__ x,
                                        const float* __restrict__ mean,
                                        const float* __restrict__ inv, int m0,
                                        int n, u16* Ah, u16* Al) {
    const int tid = threadIdx.x;
#pragma unroll
    for (int i = 0; i < 4096 / NT; ++i) {
        int chunk = tid + i * NT;      // 4096 float4 chunks
        int r = chunk >> 6;            // row 0..63
        int c4 = (chunk & 63) << 2;    // k base
        int gr = m0 + r;
        bool ok = gr < n;
        float4 v = make_float4(0.f, 0.f, 0.f, 0.f);
        if (ok) v = *(const float4*)(x + (size_t)gr * D_IN + c4);
        float4 mn = *(const float4*)(mean + c4);
        float4 iv = *(const float4*)(inv + c4);
        float a0 = ok ? (v.x - mn.x) * iv.x : 0.f;
        float a1 = ok ? (v.y - mn.y) * iv.y : 0.f;
        float a2 = ok ? (v.z - mn.z) * iv.z : 0.f;
        float a3 = ok ? (v.w - mn.w) * iv.w : 0.f;
        u16 h0 = f2bf(a0), h1 = f2bf(a1), h2 = f2bf(a2), h3 = f2bf(a3);
        u16 l0 = f2bf(a0 - bf2f(h0)), l1 = f2bf(a1 - bf2f(h1));
        u16 l2 = f2bf(a2 - bf2f(h2)), l3 = f2bf(a3 - bf2f(h3));
        int off = (r << 9) + (((c4 << 1) ^ ((r & 7) << 4)));
        u16x4 hv = {h0, h1, h2, h3};
        u16x4 lv = {l0, l1, l2, l3};
        *(u16x4*)((char*)Ah + off) = hv;
        *(u16x4*)((char*)Al + off) = lv;
    }
}

// LDS A fragment read (row stride 512B, swizzle ^((row&7)<<4))
template <int V>
__device__ __forceinline__ bf16x8 ld_frag(const u16* plane, int rowByteBase,
                                          int swz, int kbyte, int g) {
    const char* p = (const char*)plane + rowByteBase;
    if constexpr (V == 0) {
        u16x8 v = *(const u16x8*)(p + ((kbyte + (g << 4)) ^ swz));
        return __builtin_bit_cast(bf16x8, v);
    } else {
        u16x4 a = *(const u16x4*)(p + ((kbyte + (g << 3)) ^ swz));
        u16x4 b = *(const u16x4*)(p + ((kbyte + 32 + (g << 3)) ^ swz));
        u16x8 v;
        v[0] = a[0]; v[1] = a[1]; v[2] = a[2]; v[3] = a[3];
        v[4] = b[0]; v[5] = b[1]; v[6] = b[2]; v[7] = b[3];
        return __builtin_bit_cast(bf16x8, v);
    }
}

// ---- 32-k half-tile B staging: [64 n][32 k], row 64B, swz ^(((n>>1)&3)<<4) ----
// 512-thread version: 8B hi + 8B lo per thread
__device__ __forceinline__ void ldb_half(const u16* __restrict__ Gh,
                                         const u16* __restrict__ Gl, int n0,
                                         int k0, int tid, u16x4& hv, u16x4& lv) {
    int nl = tid >> 3;
    int k4 = (tid & 7) << 2;  // u16 units
    size_t goff = (size_t)(n0 + nl) * 256 + k0 + k4;
    hv = *(const u16x4*)(Gh + goff);
    lv = *(const u16x4*)(Gl + goff);
}
__device__ __forceinline__ void stb_half(u16* Bh, u16* Bl, int tid,
                                         const u16x4& hv, const u16x4& lv) {
    int nl = tid >> 3;
    int kb = (tid & 7) << 3;  // bytes
    int off = (nl << 6) + (kb ^ (((nl >> 1) & 3) << 4));
    *(u16x4*)((char*)Bh + off) = hv;
    *(u16x4*)((char*)Bl + off) = lv;
}
template <int V>
__device__ __forceinline__ bf16x8 ld_bfrag(const u16* Bp, int nl, int g) {
    const char* p = (const char*)Bp + (nl << 6);
    int swz = ((nl >> 1) & 3) << 4;
    if constexpr (V == 0) {
        u16x8 v = *(const u16x8*)(p + ((g << 4) ^ swz));
        return __builtin_bit_cast(bf16x8, v);
    } else {
        u16x4 a = *(const u16x4*)(p + ((g << 3) ^ swz));
        u16x4 b = *(const u16x4*)(p + ((32 + (g << 3)) ^ swz));
        u16x8 v;
        v[0] = a[0]; v[1] = a[1]; v[2] = a[2]; v[3] = a[3];
        v[4] = b[0]; v[5] = b[1]; v[6] = b[2]; v[7] = b[3];
        return __builtin_bit_cast(bf16x8, v);
    }
}

// one 32-k sub-step compute (8-wave): 4 A reads + 2 B reads + 6 MFMAs.
// Per-acc chain order (ah*bh, ah*bl, al*bh) identical to R12.
template <int VA, int VB>
__device__ __forceinline__ void comp_half(const u16* Ah, const u16* Al,
                                          const u16* Bh, const u16* Bl, int kbA,
                                          int wm, int wn, int c15, int g,
                                          f32x4 (&acc)[2]) {
    bf16x8 ah[2], alf[2];
#pragma unroll
    for (int mf = 0; mf < 2; ++mf) {
        int row = wm * 32 + mf * 16 + c15;
        int swz = (row & 7) << 4;
        ah[mf] = ld_frag<VA>(Ah, row << 9, swz, kbA, g);
        alf[mf] = ld_frag<VA>(Al, row << 9, swz, kbA, g);
    }
    int nl = wn * 16 + c15;
    bf16x8 bh = ld_bfrag<VB>(Bh, nl, g);
    bf16x8 bl = ld_bfrag<VB>(Bl, nl, g);
#pragma unroll
    for (int mf = 0; mf < 2; ++mf) {
        acc[mf] = __builtin_amdgcn_mfma_f32_16x16x32_bf16(ah[mf], bh, acc[mf], 0, 0, 0);
        acc[mf] = __builtin_amdgcn_mfma_f32_16x16x32_bf16(ah[mf], bl, acc[mf], 0, 0, 0);
        acc[mf] = __builtin_amdgcn_mfma_f32_16x16x32_bf16(alf[mf], bh, acc[mf], 0, 0, 0);
    }
}

// source address for global sub-step u (quad: u<64, map: u>=64)
__device__ __forceinline__ void nxt_src(int u, int mapCT,
                                        const u16* __restrict__ Bth,
                                        const u16* __restrict__ Btl,
                                        const u16* __restrict__ Wth,
                                        const u16* __restrict__ Wtl,
                                        const u16*& Gh, const u16*& Gl, int& n0,
                                        int& k0) {
    if (u < 64) {
        Gh = Bth; Gl = Btl;
        n0 = (u >> 3) << 6;
        k0 = (u & 7) << 5;
    } else {
        int um = u - 64;
        int t = um >> 3;
        int tmax = (mapCT >= 64) ? ((mapCT >> 6) - 1) : 0;
        if (t > tmax) t = tmax;
        Gh = Wth; Gl = Wtl;
        n0 = t << 6;
        k0 = (um & 7) << 5;
    }
}

// one pipeline sub-step: write buf[p^1] (regs loaded 2 steps ago), issue
// load for u+3, compute buf[p], barrier.
template <int VA, int VB>
__device__ __forceinline__ void pipe_step(const u16* Ah, const u16* Al,
                                          const u16* Bch, const u16* Bcl,
                                          u16* Bwh, u16* Bwl, u16x4& h, u16x4& l,
                                          const u16* __restrict__ Gh,
                                          const u16* __restrict__ Gl, int n0,
                                          int k0, int kbA, int tid, int wm,
                                          int wn, int c15, int g,
                                          f32x4 (&acc)[2]) {
    stb_half(Bwh, Bwl, tid, h, l);      // vmcnt data-dep wait only
    ldb_half(Gh, Gl, n0, k0, tid, h, l);
    comp_half<VA, VB>(Ah, Al, Bch, Bcl, kbA, wm, wn, c15, g, acc);
    bar_lgkm();
}

// ---------------- fused MFMA: quad-form s1,s2 + mapped GEMM (8 waves) ----------------
template <int VA, int VB>
__device__ __forceinline__ void quadmap_body(
    const float* __restrict__ x, const u16* __restrict__ Bth,
    const u16* __restrict__ Btl, const u16* __restrict__ Wth,
    const u16* __restrict__ Wtl, const float* __restrict__ mean,
    const float* __restrict__ inv, float* __restrict__ s1,
    float* __restrict__ s2, u16* __restrict__ mapped, int n, int mapCT,
    u16* Ah, u16* Al, u16* Bh0, u16* Bl0, u16* Bh1, u16* Bl1) {
    const int tid = threadIdx.x;
    const int lane = tid & 63, wave = tid >> 6;
    const int g = lane >> 4, c15 = lane & 15;
    const int wm = wave >> 2, wn = wave & 3;
    const int m0 = blockIdx.x * 64;

    stage_A<512>(x, mean, inv, m0, n, Ah, Al);
    __syncthreads();

    u16x4 hA, lA, hB, lB;
    {
        const u16 *Gh, *Gl; int n0, k0;
        nxt_src(0, mapCT, Bth, Btl, Wth, Wtl, Gh, Gl, n0, k0);
        ldb_half(Gh, Gl, n0, k0, tid, hA, lA);  // u0
        nxt_src(1, mapCT, Bth, Btl, Wth, Wtl, Gh, Gl, n0, k0);
        ldb_half(Gh, Gl, n0, k0, tid, hB, lB);  // u1
        stb_half(Bh0, Bl0, tid, hA, lA);        // buf0 <- u0
        nxt_src(2, mapCT, Bth, Btl, Wth, Wtl, Gh, Gl, n0, k0);
        ldb_half(Gh, Gl, n0, k0, tid, hA, lA);  // u2
        bar_lgkm();
    }
    // invariant entering tile u0: buf0=u0 data, hB=u0+1, hA=u0+2

    float sp[2][4] = {{0.f, 0.f, 0.f, 0.f}, {0.f, 0.f, 0.f, 0.f}};
    float* red = (float*)Bh1;  // scratch aliases buf1-hi (dead at reductions)

    // ---- quad phase: jt 0..3 -> s1 cols, 4..7 -> s2 cols ----
    for (int jt = 0; jt < 8; ++jt) {
        const int u0 = jt * 8;
        f32x4 acc[2];
        acc[0] = (f32x4){0.f, 0.f, 0.f, 0.f};
        acc[1] = (f32x4){0.f, 0.f, 0.f, 0.f};

#pragma unroll
        for (int sp2 = 0; sp2 < 4; ++sp2) {
            const u16 *Gh, *Gl; int n0, k0;
            nxt_src(u0 + sp2 * 2 + 3, mapCT, Bth, Btl, Wth, Wtl, Gh, Gl, n0, k0);
            pipe_step<VA, VB>(Ah, Al, Bh0, Bl0, Bh1, Bl1, hB, lB, Gh, Gl, n0, k0,
                              (sp2 * 2) * 64, tid, wm, wn, c15, g, acc);
            nxt_src(u0 + sp2 * 2 + 4, mapCT, Bth, Btl, Wth, Wtl, Gh, Gl, n0, k0);
            pipe_step<VA, VB>(Ah, Al, Bh1, Bl1, Bh0, Bl0, hA, lA, Gh, Gl, n0, k0,
                              (sp2 * 2 + 1) * 64, tid, wm, wn, c15, g, acc);
        }

        // epilogue: sp += Y .* xn  (C/D layout: row=(lane>>4)*4+r, col=lane&15)
        {
            int col = ((jt & 3) << 6) + wn * 16 + c15;
            float mn = mean[col], ivv = inv[col];
#pragma unroll
            for (int mf = 0; mf < 2; ++mf) {
#pragma unroll
                for (int r = 0; r < 4; ++r) {
                    int grow = m0 + wm * 32 + mf * 16 + g * 4 + r;
                    float xv = 0.f;
                    if (grow < n) xv = (x[(size_t)grow * D_IN + col] - mn) * ivv;
                    sp[mf][r] = fmaf(acc[mf][r], xv, sp[mf][r]);
                }
            }
        }
        if ((jt & 3) == 3) {
            float part[2][4];
#pragma unroll
            for (int mf = 0; mf < 2; ++mf)
#pragma unroll
                for (int r = 0; r < 4; ++r) {
                    float v = sp[mf][r];
                    v += __shfl_xor(v, 1);
                    v += __shfl_xor(v, 2);
                    v += __shfl_xor(v, 4);
                    v += __shfl_xor(v, 8);
                    part[mf][r] = v;
                    sp[mf][r] = 0.f;
                }
            // last sub-step's trailing bar => all waves done reading buf1
            if (c15 == 0) {
#pragma unroll
                for (int mf = 0; mf < 2; ++mf)
#pragma unroll
                    for (int r = 0; r < 4; ++r) {
                        int sidx = ((((((wm << 2) | g) << 1) | mf) << 4)) |
                                   (r << 2) | wn;
                        red[sidx] = part[mf][r];
                    }
            }
            bar_lgkm();  // scratch visible
            if (wn == 0 && c15 == 0) {
                float* dst = (jt < 4) ? s1 : s2;
#pragma unroll
                for (int mf = 0; mf < 2; ++mf)
#pragma unroll
                    for (int r = 0; r < 4; ++r) {
                        int sidx = ((((((wm << 2) | g) << 1) | mf) << 4)) |
                                   (r << 2);
                        float tot = (red[sidx] + red[sidx | 1]) +
                                    (red[sidx | 2] + red[sidx | 3]);
                        int grow = m0 + wm * 32 + mf * 16 + g * 4 + r;
                        if (grow < n) dst[grow] = tanhf(tot);
                    }
            }
            bar_lgkm();  // scratch reads drained before buf1 overwrite
        }
    }

    // ---- map phase: mapped[m][0..mapCT) = xn @ w, bf16 out ----
    const int tiles = mapCT >> 6;  // 0, 1 or 2
    for (int t = 0; t < tiles; ++t) {
        const int u0 = 64 + t * 8;
        f32x4 acc[2];
        acc[0] = (f32x4){0.f, 0.f, 0.f, 0.f};
        acc[1] = (f32x4){0.f, 0.f, 0.f, 0.f};

#pragma unroll
        for (int sp2 = 0; sp2 < 4; ++sp2) {
            const u16 *Gh, *Gl; int n0, k0;
            nxt_src(u0 + sp2 * 2 + 3, mapCT, Bth, Btl, Wth, Wtl, Gh, Gl, n0, k0);
            pipe_step<VA, VB>(Ah, Al, Bh0, Bl0, Bh1, Bl1, hB, lB, Gh, Gl, n0, k0,
                              (sp2 * 2) * 64, tid, wm, wn, c15, g, acc);
            nxt_src(u0 + sp2 * 2 + 4, mapCT, Bth, Btl, Wth, Wtl, Gh, Gl, n0, k0);
            pipe_step<VA, VB>(Ah, Al, Bh1, Bl1, Bh0, Bl0, hA, lA, Gh, Gl, n0, k0,
                              (sp2 * 2 + 1) * 64, tid, wm, wn, c15, g, acc);
        }
        int si = t * 64 + wn * 16 + c15;
#pragma unroll
        for (int mf = 0; mf < 2; ++mf) {
#pragma unroll
            for (int r = 0; r < 4; ++r) {
                int grow = m0 + wm * 32 + mf * 16 + g * 4 + r;
                if (grow < n)
                    mapped[(size_t)grow * mapCT + si] = f2bf(acc[mf][r]);
            }
        }
    }
}

__global__ __launch_bounds__(512, 4) void quadmap_mfma_k(
    const float* __restrict__ x, const u16* __restrict__ Bth,
    const u16* __restrict__ Btl, const u16* __restrict__ Wth,
    const u16* __restrict__ Wtl, const float* __restrict__ mean,
    const float* __restrict__ inv, float* __restrict__ s1,
    float* __restrict__ s2, u16* __restrict__ mapped,
    const int* __restrict__ flagp, int n, int mapCT) {
    __shared__ u16 Ah[64 * 256];
    __shared__ u16 Al[64 * 256];
    __shared__ u16 Bh0[64 * 32];
    __shared__ u16 Bl0[64 * 32];
    __shared__ u16 Bh1[64 * 32];
    __shared__ u16 Bl1[64 * 32];
    int v = flagp[0];
    if (v == 1)
        quadmap_body<0, 1>(x, Bth, Btl, Wth, Wtl, mean, inv, s1, s2, mapped, n, mapCT, Ah, Al, Bh0, Bl0, Bh1, Bl1);
    else if (v == 2)
        quadmap_body<1, 0>(x, Bth, Btl, Wth, Wtl, mean, inv, s1, s2, mapped, n, mapCT, Ah, Al, Bh0, Bl0, Bh1, Bl1);
    else if (v == 3)
        quadmap_body<1, 1>(x, Bth, Btl, Wth, Wtl, mean, inv, s1, s2, mapped, n, mapCT, Ah, Al, Bh0, Bl0, Bh1, Bl1);
    else
        quadmap_body<0, 0>(x, Bth, Btl, Wth, Wtl, mean, inv, s1, s2, mapped, n, mapCT, Ah, Al, Bh0, Bl0, Bh1, Bl1);
}

// ---------------- standalone MFMA mapped GEMM (CT=64 tier; R11 structure) ----------------
__device__ __forceinline__ void ldb_regs(const u16* __restrict__ Gh,
                                         const u16* __restrict__ Gl, int n0,
                                         int k0, int tid, u16x8 (&hv)[2],
                                         u16x8 (&lv)[2]) {
#pragma unroll
    for (int i = 0; i < 2; ++i) {
        int chunk = tid + (i << 8);
        int nl = chunk >> 3;
        int k8 = (chunk & 7) << 3;
        size_t goff = (size_t)(n0 + nl) * 256 + k0 + k8;
        hv[i] = *(const u16x8*)(Gh + goff);
        lv[i] = *(const u16x8*)(Gl + goff);
    }
}
__device__ __forceinline__ void stb_lds(u16* Bh, u16* Bl, int tid,
                                        const u16x8 (&hv)[2],
                                        const u16x8 (&lv)[2]) {
#pragma unroll
    for (int i = 0; i < 2; ++i) {
        int chunk = tid + (i << 8);
        int nl = chunk >> 3;
        int k8 = (chunk & 7) << 3;
        int off = (nl << 7) + (((k8 << 1) ^ ((nl & 7) << 4)));
        *(u16x8*)((char*)Bh + off) = hv[i];
        *(u16x8*)((char*)Bl + off) = lv[i];
    }
}
template <int VA, int VB>
__device__ __forceinline__ void comp_kt(const u16* Ah, const u16* Al,
                                        const u16* Bh, const u16* Bl, int kt,
                                        int wm, int wn, int c15, int g,
                                        f32x4 (&acc)[2][2]) {
#pragma unroll
    for (int kk = 0; kk < 2; ++kk) {
        int kbA = kt * 128 + kk * 64;
        int kbB = kk * 64;
        bf16x8 ah[2], alf[2], bhf[2], blf[2];
#pragma unroll
        for (int mf = 0; mf < 2; ++mf) {
            int row = wm * 32 + mf * 16 + c15;
            int swz = (row & 7) << 4;
            ah[mf] = ld_frag<VA>(Ah, row << 9, swz, kbA, g);
            alf[mf] = ld_frag<VA>(Al, row << 9, swz, kbA, g);
        }
#pragma unroll
        for (int nf = 0; nf < 2; ++nf) {
            int nl = wn * 32 + nf * 16 + c15;
            int swz = (nl & 7) << 4;
            bhf[nf] = ld_frag<VB>(Bh, nl << 7, swz, kbB, g);
            blf[nf] = ld_frag<VB>(Bl, nl << 7, swz, kbB, g);
        }
#pragma unroll
        for (int mf = 0; mf < 2; ++mf)
#pragma unroll
            for (int nf = 0; nf < 2; ++nf) {
                acc[mf][nf] = __builtin_amdgcn_mfma_f32_16x16x32_bf16(
                    ah[mf], bhf[nf], acc[mf][nf], 0, 0, 0);
                acc[mf][nf] = __builtin_amdgcn_mfma_f32_16x16x32_bf16(
                    ah[mf], blf[nf], acc[mf][nf], 0, 0, 0);
                acc[mf][nf] = __builtin_amdgcn_mfma_f32_16x16x32_bf16(
                    alf[mf], bhf[nf], acc[mf][nf], 0, 0, 0);
            }
    }
}

template <int VA, int VB>
__device__ __forceinline__ void map_body(
    const float* __restrict__ x, const u16* __restrict__ Wth,
    const u16* __restrict__ Wtl, const float* __restrict__ mean,
    const float* __restrict__ inv, u16* __restrict__ mapped, int n, int c0,
    int CT, u16* Ah, u16* Al, u16* Bh, u16* Bl) {
    const int tid = threadIdx.x;
    const int lane = tid & 63, wave = tid >> 6;
    const int g = lane >> 4, c15 = lane & 15;
    const int wm = wave >> 1, wn = wave & 1;
    const int m0 = blockIdx.x * 64;

    stage_A<256>(x, mean, inv, m0, n, Ah, Al);
    __syncthreads();

    u16x8 rbh[2], rbl[2];
    ldb_regs(Wth, Wtl, c0, 0, tid, rbh, rbl);

    const int tiles = CT >> 6;
    for (int t = 0; t < tiles; ++t) {
        f32x4 acc[2][2];
#pragma unroll
        for (int mf = 0; mf < 2; ++mf)
#pragma unroll
            for (int nf = 0; nf < 2; ++nf) acc[mf][nf] = (f32x4){0.f, 0.f, 0.f, 0.f};

        for (int kt = 0; kt < 4; ++kt) {
            bar_lgkm();
            stb_lds(Bh, Bl, tid, rbh, rbl);
            int nn0 = (kt < 3) ? c0 + t * 64
                               : c0 + ((t + 1 < tiles) ? (t + 1) * 64 : t * 64);
            int nk0 = (kt < 3) ? (kt + 1) * 64 : 0;
            ldb_regs(Wth, Wtl, nn0, nk0, tid, rbh, rbl);
            bar_lgkm();
            comp_kt<VA, VB>(Ah, Al, Bh, Bl, kt, wm, wn, c15, g, acc);
        }
#pragma unroll
        for (int mf = 0; mf < 2; ++mf)
#pragma unroll
            for (int nf = 0; nf < 2; ++nf) {
                int si = t * 64 + wn * 32 + nf * 16 + c15;
#pragma unroll
                for (int r = 0; r < 4; ++r) {
                    int grow = m0 + wm * 32 + mf * 16 + g * 4 + r;
                    if (grow < n) mapped[(size_t)grow * CT + si] = f2bf(acc[mf][nf][r]);
                }
            }
    }
}

__global__ __launch_bounds__(256) void map_mfma_k(
    const float* __restrict__ x, const u16* __restrict__ Wth,
    const u16* __restrict__ Wtl, const float* __restrict__ mean,
    const float* __restrict__ inv, u16* __restrict__ mapped, int n, int c0,
    int CT, const int* __restrict__ flagp) {
    __shared__ u16 Ah[64 * 256];
    __shared__ u16 Al[64 * 256];
    __shared__ u16 Bh[64 * 64];
    __shared__ u16 Bl[64 * 64];
    int v = flagp[0];
    if (v == 1) map_body<0, 1>(x, Wth, Wtl, mean, inv, mapped, n, c0, CT, Ah, Al, Bh, Bl);
    else if (v == 2) map_body<1, 0>(x, Wth, Wtl, mean, inv, mapped, n, c0, CT, Ah, Al, Bh, Bl);
    else if (v == 3) map_body<1, 1>(x, Wth, Wtl, mean, inv, mapped, n, c0, CT, Ah, Al, Bh, Bl);
    else map_body<0, 0>(x, Wth, Wtl, mean, inv, mapped, n, c0, CT, Ah, Al, Bh, Bl);
}

// ---------------- fp32 mapped GEMM fallback (tiny-ws tiers, CT<64) ----------------
template <typename OT>
__global__ __launch_bounds__(256) void gemm_map_k(const float* __restrict__ x,
                                                  const float* __restrict__ w,
                                                  const float* __restrict__ mean,
                                                  const float* __restrict__ inv,
                                                  OT* __restrict__ outp, int n,
                                                  int c0, int CT) {
    __shared__ float As[64][68];
    __shared__ float Bs[64][68];
    const int tid = threadIdx.x;
    const int tx = tid & 15, ty = tid >> 4;
    const int m0 = blockIdx.x * 64;
    const int tiles = (CT + 63) >> 6;

    for (int t = 0; t < tiles; ++t) {
        const int jt = c0 + (t << 6);
        float acc[4][4];
#pragma unroll
        for (int a = 0; a < 4; ++a)
#pragma unroll
            for (int b = 0; b < 4; ++b) acc[a][b] = 0.f;

        for (int kt = 0; kt < D_IN; kt += 64) {
#pragma unroll
            for (int i = 0; i < 4; ++i) {
                int f4 = tid + 256 * i;
                int r = f4 >> 4;
                int c4 = (f4 & 15) << 2;
                float4 o;
                int gr = m0 + r;
                if (gr < n) {
                    float4 v = *(const float4*)(x + (size_t)gr * D_IN + kt + c4);
                    float4 mn = *(const float4*)(mean + kt + c4);
                    float4 iv = *(const float4*)(inv + kt + c4);
                    o.x = (v.x - mn.x) * iv.x;
                    o.y = (v.y - mn.y) * iv.y;
                    o.z = (v.z - mn.z) * iv.z;
                    o.w = (v.w - mn.w) * iv.w;
                } else {
                    o = make_float4(0.f, 0.f, 0.f, 0.f);
                }
                *(float4*)&As[r][c4] = o;
            }
#pragma unroll
            for (int i = 0; i < 4; ++i) {
                int f4 = tid + 256 * i;
                int r = f4 >> 4;
                int c4 = (f4 & 15) << 2;
                int jc = jt + c4;
                float4 bv = (jc < D_OUT)
                                ? *(const float4*)(w + (size_t)(kt + r) * D_OUT + jc)
                                : make_float4(0.f, 0.f, 0.f, 0.f);
                *(float4*)&Bs[r][c4] = bv;
            }
            __syncthreads();
#pragma unroll 8
            for (int k = 0; k < 64; ++k) {
                float4 bv = *(const float4*)&Bs[k][tx << 2];
                float a0 = As[(ty << 2) + 0][k];
                float a1 = As[(ty << 2) + 1][k];
                float a2 = As[(ty << 2) + 2][k];
                float a3 = As[(ty << 2) + 3][k];
                acc[0][0] = fmaf(a0, bv.x, acc[0][0]);
                acc[0][1] = fmaf(a0, bv.y, acc[0][1]);
                acc[0][2] = fmaf(a0, bv.z, acc[0][2]);
                acc[0][3] = fmaf(a0, bv.w, acc[0][3]);
                acc[1][0] = fmaf(a1, bv.x, acc[1][0]);
                acc[1][1] = fmaf(a1, bv.y, acc[1][1]);
                acc[1][2] = fmaf(a1, bv.z, acc[1][2]);
                acc[1][3] = fmaf(a1, bv.w, acc[1][3]);
                acc[2][0] = fmaf(a2, bv.x, acc[2][0]);
                acc[2][1] = fmaf(a2, bv.y, acc[2][1]);
                acc[2][2] = fmaf(a2, bv.z, acc[2][2]);
                acc[2][3] = fmaf(a2, bv.w, acc[2][3]);
                acc[3][0] = fmaf(a3, bv.x, acc[3][0]);
                acc[3][1] = fmaf(a3, bv.y, acc[3][1]);
                acc[3][2] = fmaf(a3, bv.z, acc[3][2]);
                acc[3][3] = fmaf(a3, bv.w, acc[3][3]);
            }
            __syncthreads();
        }
        int si = (jt - c0) + (tx << 2);
        if (si < CT) {
#pragma unroll
            for (int a = 0; a < 4; ++a) {
                int gm = m0 + (ty << 2) + a;
                if (gm < n) {
                    ushort4 pk;
                    pk.x = f2bf(acc[a][0]);
                    pk.y = f2bf(acc[a][1]);
                    pk.z = f2bf(acc[a][2]);
                    pk.w = f2bf(acc[a][3]);
                    *(ushort4*)((u16*)outp + (size_t)gm * CT + si) = pk;
                }
            }
        }
    }
}

// ---------------- CSR row_ptr from sorted rows ----------------
__global__ void build_rowptr_k(const int* __restrict__ rows, int E, int n,
                               int* __restrict__ rp) {
    int e = blockIdx.x * blockDim.x + threadIdx.x;
    if (e >= E) return;
    int r = rows[e];
    int prev = (e == 0) ? -1 : rows[e - 1];
    for (int q = prev + 1; q <= r; ++q) rp[q] = e;
    if (e == E - 1) {
        for (int q = r + 1; q <= n; ++q) rp[q] = E;
    }
}

// ---------------- per-row softmax stats (max, 1/denom) [+ alpha] ----------------
template <bool WRITE_ALPHA>
__global__ __launch_bounds__(256) void row_softmax_k(
    const int* __restrict__ row_ptr, const int* __restrict__ cols,
    const float* __restrict__ ev, const float* __restrict__ s1,
    const float* __restrict__ s2, float* __restrict__ rmax,
    float* __restrict__ rsm, float* __restrict__ alpha, int n) {
    int wave = threadIdx.x >> 6;
    int lane = threadIdx.x & 63;
    int row = blockIdx.x * 4 + wave;
    if (row >= n) return;
    int e0 = row_ptr[row], e1 = row_ptr[row + 1];
    if (e0 >= e1) {
        if (lane == 0) {
            rmax[row] = 0.f;
            rsm[row] = 0.f;
        }
        return;
    }
    float s1r = s1[row];
    float mx = -1e30f;
    for (int e = e0 + lane; e < e1; e += 64) {
        float v = ev[e] * (s1r + s2[cols[e]]);
        v = v > 0.f ? v : LEAKY * v;
        mx = fmaxf(mx, v);
    }
#pragma unroll
    for (int off = 32; off; off >>= 1) mx = fmaxf(mx, __shfl_xor(mx, off));
    float sm = 0.f;
    for (int e = e0 + lane; e < e1; e += 64) {
        float v = ev[e] * (s1r + s2[cols[e]]);
        v = v > 0.f ? v : LEAKY * v;
        sm += __expf(v - mx);
    }
#pragma unroll
    for (int off = 32; off; off >>= 1) sm += __shfl_xor(sm, off);
    float rsm_v = 1.f / sm;
    if (lane == 0) {
        rmax[row] = mx;
        rsm[row] = rsm_v;
    }
    if constexpr (WRITE_ALPHA) {
        for (int e = e0 + lane; e < e1; e += 64) {
            float v = ev[e] * (s1r + s2[cols[e]]);
            v = v > 0.f ? v : LEAKY * v;
            alpha[e] = __expf(v - mx) * rsm_v;
        }
    }
}

// ---------------- gather v2: chunked cols/alpha preload + 8-wide MLP ----------------
template <bool HAS_ALPHA>
__global__ __launch_bounds__(256) void attn_gather2_k(
    const int* __restrict__ row_ptr, const int* __restrict__ cols,
    const float* __restrict__ alpha, const float* __restrict__ ev,
    const float* __restrict__ s1, const float* __restrict__ s2,
    const float* __restrict__ rmax, const float* __restrict__ rsm,
    const u16* __restrict__ mapped, float* __restrict__ outp, int n, int c0,
    int CT) {
    const int wave = threadIdx.x >> 6;
    const int lane = threadIdx.x & 63;
    const int row = blockIdx.x * 4 + wave;
    if (row >= n) return;
    const int e0 = row_ptr[row], e1 = row_ptr[row + 1];
    float* orow = outp + (size_t)row * D_OUT + c0;
    const int nu = CT >> 1;  // u32 words per mapped row
    const bool act = lane < nu;
    if (e0 >= e1) {
        if (act) *(float2*)(orow + (lane << 1)) = make_float2(0.f, 0.f);
        return;
    }
    float s1r = 0.f, mxv = 0.f, rsv = 0.f;
    if constexpr (!HAS_ALPHA) {
        s1r = s1[row];
        mxv = rmax[row];
        rsv = rsm[row];
    }
    const u32* map32 = (const u32*)mapped;
    float ox = 0.f, oy = 0.f;
    int e = e0;
    while (e < e1) {
        int cnt = min(e1 - e, 64);
        int ce = 0;
        float ae = 0.f;
        if (lane < cnt) {
            int ee = e + lane;
            ce = cols[ee];
            if constexpr (HAS_ALPHA) {
                ae = alpha[ee];
            } else {
                float v = ev[ee] * (s1r + s2[ce]);
                v = v > 0.f ? v : LEAKY * v;
                ae = __expf(v - mxv) * rsv;
            }
        }
        for (int j0 = 0; j0 < cnt; j0 += 8) {
            int cv[8];
            float av[8];
            u32 mv[8];
#pragma unroll
            for (int j = 0; j < 8; ++j) {
                cv[j] = __shfl(ce, j0 + j);
                av[j] = __shfl(ae, j0 + j);
            }
#pragma unroll
            for (int j = 0; j < 8; ++j)
                mv[j] = act ? map32[(size_t)cv[j] * nu + lane] : 0u;
#pragma unroll
            for (int j = 0; j < 8; ++j) {
                ox = fmaf(av[j], bf2f((u16)(mv[j] & 0xffffu)), ox);
                oy = fmaf(av[j], bf2f((u16)(mv[j] >> 16)), oy);
            }
        }
        e += cnt;
    }
    if (act) *(float2*)(orow + (lane << 1)) = make_float2(ox, oy);
}

extern "C" void kernel_launch(void* const* d_in, const int* in_sizes, int n_in,
                              void* d_out, int out_size, void* d_ws, size_t ws_size,
                              hipStream_t stream) {
    const float* x  = (const float*)d_in[0];
    const float* w  = (const float*)d_in[1];
    const float* w1 = (const float*)d_in[2];
    const float* w2 = (const float*)d_in[3];
    const float* ev = (const float*)d_in[4];
    const int* rows = (const int*)d_in[5];
    const int* cols = (const int*)d_in[6];
    float* out = (float*)d_out;

    const int N = in_sizes[0] / D_IN;
    const int E = in_sizes[4];

    // ---- ws layout ----
    char* base = (char*)d_ws;
    size_t off = 0;
    auto alloc = [&](size_t bytes) -> char* {
        off = (off + 255) & ~(size_t)255;
        char* p = base + off;
        off += bytes;
        return p;
    };
    float* sums  = (float*)alloc(256 * 4);
    float* sqs   = (float*)alloc(256 * 4);
    float* mean  = (float*)alloc(256 * 4);
    float* inv   = (float*)alloc(256 * 4);
    float* s1    = (float*)alloc((size_t)N * 4);
    float* s2    = (float*)alloc((size_t)N * 4);
    float* rmax  = (float*)alloc((size_t)N * 4);
    float* rsm   = (float*)alloc((size_t)N * 4);
    int* row_ptr = (int*)alloc((size_t)(N + 1) * 4);
    int* flag    = (int*)alloc(256);
    u16* Bth = (u16*)alloc((size_t)512 * 256 * 2);
    u16* Btl = (u16*)alloc((size_t)512 * 256 * 2);
    u16* Wth = (u16*)alloc((size_t)128 * 256 * 2);
    u16* Wtl = (u16*)alloc((size_t)128 * 256 * 2);
    size_t head0 = off;

    size_t alpha_bytes = (size_t)E * 4;
    auto fits_alpha = [&](size_t mapped_bytes) {
        size_t o = (head0 + 255) & ~(size_t)255;
        o += alpha_bytes;
        o = (o + 255) & ~(size_t)255;
        return o + mapped_bytes <= ws_size;
    };
    auto fits_noalpha = [&](size_t mapped_bytes) {
        size_t o = (head0 + 255) & ~(size_t)255;
        return o + mapped_bytes <= ws_size;
    };

    bool has_alpha;
    int CT;
    if (fits_alpha((size_t)N * 128 * 2)) {
        has_alpha = true; CT = 128;
    } else if (fits_alpha((size_t)N * 64 * 2)) {
        has_alpha = true; CT = 64;
    } else if (fits_noalpha((size_t)N * 32 * 2)) {
        has_alpha = false; CT = 32;
    } else if (fits_noalpha((size_t)N * 16 * 2)) {
        has_alpha = false; CT = 16;
    } else {
        has_alpha = false; CT = 8;
    }
    float* alpha = has_alpha ? (float*)alloc(alpha_bytes) : nullptr;
    u16* mapped = (u16*)alloc((size_t)N * CT * 2);

    // ---- pipeline ----
    hipMemsetAsync(sums, 0, 512 * sizeof(float), stream);
    colstats_k<<<512, 256, 0, stream>>>(x, N, sums, sqs);
    finalize_k<<<1, 256, 0, stream>>>(sums, sqs, N, mean, inv);
    prep_w_k<<<640, 256, 0, stream>>>(w1, w2, w, Bth, Btl, Wth, Wtl);
    probe_k<<<1, 64, 0, stream>>>(flag);

    int qb = (N + 63) / 64;
    int mapCT = (CT >= 64) ? CT : 0;  // fused map covers cols [0, min(CT,128))
    quadmap_mfma_k<<<qb, 512, 0, stream>>>(x, Bth, Btl, Wth, Wtl, mean, inv, s1,
                                           s2, mapped, flag, N, mapCT);

    build_rowptr_k<<<(E + 255) / 256, 256, 0, stream>>>(rows, E, N, row_ptr);
    int ab = (N + 3) / 4;
    if (has_alpha) {
        row_softmax_k<true><<<ab, 256, 0, stream>>>(row_ptr, cols, ev, s1, s2,
                                                    rmax, rsm, alpha, N);
    } else {
        row_softmax_k<false><<<ab, 256, 0, stream>>>(row_ptr, cols, ev, s1, s2,
                                                     rmax, rsm, nullptr, N);
    }

    if (CT == 128) {
        attn_gather2_k<true><<<ab, 256, 0, stream>>>(
            row_ptr, cols, alpha, ev, s1, s2, rmax, rsm, mapped, out, N, 0, CT);
    } else if (CT == 64) {
        attn_gather2_k<true><<<ab, 256, 0, stream>>>(
            row_ptr, cols, alpha, ev, s1, s2, rmax, rsm, mapped, out, N, 0, 64);
        map_mfma_k<<<qb, 256, 0, stream>>>(x, Wth, Wtl, mean, inv, mapped, N, 64,
                                           64, flag);
        attn_gather2_k<true><<<ab, 256, 0, stream>>>(
            row_ptr, cols, alpha, ev, s1, s2, rmax, rsm, mapped, out, N, 64, 64);
    } else {
        for (int c0 = 0; c0 < D_OUT; c0 += CT) {
            gemm_map_k<u16><<<qb, 256, 0, stream>>>(x, w, mean, inv, mapped, N,
                                                    c0, CT);
            attn_gather2_k<false><<<ab, 256, 0, stream>>>(
                row_ptr, cols, nullptr, ev, s1, s2, rmax, rsm, mapped, out, N,
                c0, CT);
        }
    }
}

// Round 8
// 581.151 us; speedup vs baseline: 1.2390x; 1.2390x over previous
//
#include <hip/hip_runtime.h>

// AliNetGraphAttentionLayer: N=100000, E=1600000, D_IN=256, D_OUT=128
// R15 = R14 resubmit (R14 bench was an infra container failure, never ran).
// R11 shell (4 waves, 256 thr, known-good 227us) with j-tile PAIRS:
// wave (wm,wj) owns 32 rows x 64 cols (acc[2][4]); B staged [128n][32k]
// single-buffered; 80KB LDS, 2 blocks/CU. Block does 96 MFMAs per 48
// b128 LDS reads (was 48/32) and half the barriers. Per-(row,col) MFMA
// chains identical -> mapped bitwise-identical; s1/s2 regroup ~1e-7.
// colstats/softmax/gather identical to R11.
#define D_IN 256
#define D_OUT 128
#define EPS_BN 1e-3f
#define LEAKY 0.2f

typedef unsigned short u16;
typedef unsigned int u32;
typedef u16 u16x4 __attribute__((ext_vector_type(4)));
typedef u16 u16x8 __attribute__((ext_vector_type(8)));
typedef __bf16 bf16x8 __attribute__((ext_vector_type(8)));
typedef float f32x4 __attribute__((ext_vector_type(4)));

__device__ __forceinline__ float bf2f(u16 u) {
    u32 v = ((u32)u) << 16;
    return __uint_as_float(v);
}
__device__ __forceinline__ u16 f2bf(float f) {
    u32 u = __float_as_uint(f);
    u32 r = (u + 0x7FFFu + ((u >> 16) & 1u)) >> 16;  // RNE
    return (u16)r;
}

// raw barrier with LDS-only drain: global loads stay in flight across it
__device__ __forceinline__ void bar_lgkm() {
    asm volatile("s_waitcnt lgkmcnt(0)" ::: "memory");
    __builtin_amdgcn_s_barrier();
    asm volatile("" ::: "memory");
}

// ---------------- column stats (R11 version) ----------------
__global__ void colstats_k(const float* __restrict__ x, int n,
                           float* __restrict__ sums, float* __restrict__ sqs) {
    int c = threadIdx.x;
    float s = 0.f, q = 0.f;
    for (int r = blockIdx.x; r < n; r += gridDim.x) {
        float v = x[(size_t)r * D_IN + c];
        s += v;
        q += v * v;
    }
    atomicAdd(&sums[c], s);
    atomicAdd(&sqs[c], q);
}

__global__ void finalize_k(const float* __restrict__ sums, const float* __restrict__ sqs,
                           int n, float* __restrict__ mean, float* __restrict__ inv) {
    int c = threadIdx.x;
    float m = sums[c] / (float)n;
    float v = sqs[c] / (float)n - m * m;
    mean[c] = m;
    inv[c] = rsqrtf(v + EPS_BN);
}

// ---------------- W split prep: Bt[n][k] = W[k][n] as hi/lo bf16 ----------------
__global__ void prep_w_k(const float* __restrict__ w1, const float* __restrict__ w2,
                         const float* __restrict__ w, u16* __restrict__ Bth,
                         u16* __restrict__ Btl, u16* __restrict__ Wth,
                         u16* __restrict__ Wtl) {
    int idx = blockIdx.x * 256 + threadIdx.x;  // 640*256 threads
    int k = idx & 255;
    int nn = idx >> 8;
    if (nn < 512) {
        float v = (nn < 256) ? w1[(size_t)k * 256 + nn]
                             : w2[(size_t)k * 256 + (nn - 256)];
        u16 h = f2bf(v);
        u16 l = f2bf(v - bf2f(h));
        Bth[(size_t)nn * 256 + k] = h;
        Btl[(size_t)nn * 256 + k] = l;
    } else {
        int nm = nn - 512;  // output col 0..127
        float v = w[(size_t)k * D_OUT + nm];
        u16 h = f2bf(v);
        u16 l = f2bf(v - bf2f(h));
        Wth[(size_t)nm * 256 + k] = h;
        Wtl[(size_t)nm * 256 + k] = l;
    }
}

// ---------------- MFMA fragment-layout probe ----------------
__device__ __forceinline__ int kmap(int v, int g, int j) {
    return (v == 0) ? (8 * g + j) : (16 * (j >> 2) + 4 * g + (j & 3));
}

__global__ void probe_k(int* __restrict__ flagp) {
    __shared__ float Ar[16][32];
    __shared__ float Br[32][16];
    __shared__ float Dr[16][16];
    int l = threadIdx.x;  // 64 threads
    for (int i = l; i < 512; i += 64) {
        int r = i >> 5, k = i & 31;
        Ar[r][k] = (float)(((r * 5 + k * 3) % 11) - 5);
    }
    for (int i = l; i < 512; i += 64) {
        int k = i >> 4, c = i & 15;
        Br[k][c] = (float)(((k * 3 + c * 7) % 13) - 6);
    }
    __syncthreads();
    for (int i = l; i < 256; i += 64) {
        int r = i >> 4, c = i & 15;
        float s = 0.f;
        for (int k = 0; k < 32; ++k) s += Ar[r][k] * Br[k][c];
        Dr[r][c] = s;
    }
    __syncthreads();
    int g = l >> 4, c15 = l & 15;
    int found = -1;
    for (int combo = 0; combo < 4; ++combo) {
        int va = combo >> 1, vb = combo & 1;
        u16x8 af, bfv;
#pragma unroll
        for (int j = 0; j < 8; ++j) {
            af[j] = f2bf(Ar[c15][kmap(va, g, j)]);
            bfv[j] = f2bf(Br[kmap(vb, g, j)][c15]);
        }
        f32x4 d = {0.f, 0.f, 0.f, 0.f};
        d = __builtin_amdgcn_mfma_f32_16x16x32_bf16(
            __builtin_bit_cast(bf16x8, af), __builtin_bit_cast(bf16x8, bfv), d,
            0, 0, 0);
        bool ok = true;
#pragma unroll
        for (int r = 0; r < 4; ++r) ok = ok && (d[r] == Dr[g * 4 + r][c15]);
        if (found < 0 && __all(ok)) found = combo;
    }
    if (l == 0) flagp[0] = (found < 0) ? 0 : found;
}

// ---------------- staging helpers ----------------
// A planes: [64 rows][256 k] bf16, row stride 512 B, swizzle byte^=(row&7)<<4
template <int NT>
__device__ __forceinline__ void stage_A(const float* __restrict__ x,
                                        const float* __restrict__ mean,
                                        const float* __restrict__ inv, int m0,
                                        int n, u16* Ah, u16* Al) {
    const int tid = threadIdx.x;
#pragma unroll
    for (int i = 0; i < 4096 / NT; ++i) {
        int chunk = tid + i * NT;      // 4096 float4 chunks
        int r = chunk >> 6;            // row 0..63
        int c4 = (chunk & 63) << 2;    // k base
        int gr = m0 + r;
        bool ok = gr < n;
        float4 v = make_float4(0.f, 0.f, 0.f, 0.f);
        if (ok) v = *(const float4*)(x + (size_t)gr * D_IN + c4);
        float4 mn = *(const float4*)(mean + c4);
        float4 iv = *(const float4*)(inv + c4);
        float a0 = ok ? (v.x - mn.x) * iv.x : 0.f;
        float a1 = ok ? (v.y - mn.y) * iv.y : 0.f;
        float a2 = ok ? (v.z - mn.z) * iv.z : 0.f;
        float a3 = ok ? (v.w - mn.w) * iv.w : 0.f;
        u16 h0 = f2bf(a0), h1 = f2bf(a1), h2 = f2bf(a2), h3 = f2bf(a3);
        u16 l0 = f2bf(a0 - bf2f(h0)), l1 = f2bf(a1 - bf2f(h1));
        u16 l2 = f2bf(a2 - bf2f(h2)), l3 = f2bf(a3 - bf2f(h3));
        int off = (r << 9) + (((c4 << 1) ^ ((r & 7) << 4)));
        u16x4 hv = {h0, h1, h2, h3};
        u16x4 lv = {l0, l1, l2, l3};
        *(u16x4*)((char*)Ah + off) = hv;
        *(u16x4*)((char*)Al + off) = lv;
    }
}

// LDS A fragment read (row stride 512B, swizzle ^((row&7)<<4))
template <int V>
__device__ __forceinline__ bf16x8 ld_frag(const u16* plane, int rowByteBase,
                                          int swz, int kbyte, int g) {
    const char* p = (const char*)plane + rowByteBase;
    if constexpr (V == 0) {
        u16x8 v = *(const u16x8*)(p + ((kbyte + (g << 4)) ^ swz));
        return __builtin_bit_cast(bf16x8, v);
    } else {
        u16x4 a = *(const u16x4*)(p + ((kbyte + (g << 3)) ^ swz));
        u16x4 b = *(const u16x4*)(p + ((kbyte + 32 + (g << 3)) ^ swz));
        u16x8 v;
        v[0] = a[0]; v[1] = a[1]; v[2] = a[2]; v[3] = a[3];
        v[4] = b[0]; v[5] = b[1]; v[6] = b[2]; v[7] = b[3];
        return __builtin_bit_cast(bf16x8, v);
    }
}

// ---- B pair-tile staging: [128 n][32 k], row 64B, swz ^(((n>>1)&3)<<4) ----
__device__ __forceinline__ void ldb2(const u16* __restrict__ Gh,
                                     const u16* __restrict__ Gl, int n0, int k0,
                                     int tid, u16x8 (&hv)[2], u16x8 (&lv)[2]) {
#pragma unroll
    for (int i = 0; i < 2; ++i) {
        int chunk = tid + (i << 8);   // 512 chunks of 8 u16
        int nl = chunk >> 2;          // row 0..127
        int k8 = (chunk & 3) << 3;    // u16 units within 32-k
        size_t goff = (size_t)(n0 + nl) * 256 + k0 + k8;
        hv[i] = *(const u16x8*)(Gh + goff);
        lv[i] = *(const u16x8*)(Gl + goff);
    }
}
__device__ __forceinline__ void stb2(u16* Bh, u16* Bl, int tid,
                                     const u16x8 (&hv)[2], const u16x8 (&lv)[2]) {
#pragma unroll
    for (int i = 0; i < 2; ++i) {
        int chunk = tid + (i << 8);
        int nl = chunk >> 2;
        int kb = (chunk & 3) << 4;    // bytes
        int off = (nl << 6) + (kb ^ (((nl >> 1) & 3) << 4));
        *(u16x8*)((char*)Bh + off) = hv[i];
        *(u16x8*)((char*)Bl + off) = lv[i];
    }
}
template <int V>
__device__ __forceinline__ bf16x8 ld_bfrag(const u16* Bp, int nl, int g) {
    const char* p = (const char*)Bp + (nl << 6);
    int swz = ((nl >> 1) & 3) << 4;
    if constexpr (V == 0) {
        u16x8 v = *(const u16x8*)(p + ((g << 4) ^ swz));
        return __builtin_bit_cast(bf16x8, v);
    } else {
        u16x4 a = *(const u16x4*)(p + ((g << 3) ^ swz));
        u16x4 b = *(const u16x4*)(p + ((32 + (g << 3)) ^ swz));
        u16x8 v;
        v[0] = a[0]; v[1] = a[1]; v[2] = a[2]; v[3] = a[3];
        v[4] = b[0]; v[5] = b[1]; v[6] = b[2]; v[7] = b[3];
        return __builtin_bit_cast(bf16x8, v);
    }
}

// one 32-k sub-step per wave: 4 A reads + 8 B reads + 24 MFMAs.
// Per-acc chain order (ah*bh, ah*bl, al*bh) identical to R11.
template <int VA, int VB>
__device__ __forceinline__ void comp32(const u16* Ah, const u16* Al,
                                       const u16* Bh, const u16* Bl, int kbA,
                                       int wm, int wj, int c15, int g,
                                       f32x4 (&acc)[2][4]) {
    bf16x8 ah[2], alf[2];
#pragma unroll
    for (int mf = 0; mf < 2; ++mf) {
        int row = wm * 32 + mf * 16 + c15;
        int swz = (row & 7) << 4;
        ah[mf] = ld_frag<VA>(Ah, row << 9, swz, kbA, g);
        alf[mf] = ld_frag<VA>(Al, row << 9, swz, kbA, g);
    }
    bf16x8 bh[4], bl[4];
#pragma unroll
    for (int nf = 0; nf < 4; ++nf) {
        int nl = wj * 64 + nf * 16 + c15;
        bh[nf] = ld_bfrag<VB>(Bh, nl, g);
        bl[nf] = ld_bfrag<VB>(Bl, nl, g);
    }
#pragma unroll
    for (int mf = 0; mf < 2; ++mf)
#pragma unroll
        for (int nf = 0; nf < 4; ++nf) {
            acc[mf][nf] = __builtin_amdgcn_mfma_f32_16x16x32_bf16(
                ah[mf], bh[nf], acc[mf][nf], 0, 0, 0);
            acc[mf][nf] = __builtin_amdgcn_mfma_f32_16x16x32_bf16(
                ah[mf], bl[nf], acc[mf][nf], 0, 0, 0);
            acc[mf][nf] = __builtin_amdgcn_mfma_f32_16x16x32_bf16(
                alf[mf], bh[nf], acc[mf][nf], 0, 0, 0);
        }
}

// global source for sub-step u: u<32 quad pairs (Bt), u>=32 map pair (Wt)
__device__ __forceinline__ void nxt_src2(int u, int totSub,
                                         const u16* __restrict__ Bth,
                                         const u16* __restrict__ Btl,
                                         const u16* __restrict__ Wth,
                                         const u16* __restrict__ Wtl,
                                         const u16*& Gh, const u16*& Gl,
                                         int& n0, int& k0) {
    if (u >= totSub) u = totSub - 1;
    if (u < 32) {
        Gh = Bth; Gl = Btl;
        n0 = (u >> 3) << 7;   // pair p * 128
        k0 = (u & 7) << 5;
    } else {
        Gh = Wth; Gl = Wtl;
        n0 = 0;
        k0 = (u & 7) << 5;
    }
}

// ---------------- fused MFMA: quad-form s1,s2 + mapped GEMM (4 waves) ----------------
template <int VA, int VB>
__device__ __forceinline__ void quadmap_body(
    const float* __restrict__ x, const u16* __restrict__ Bth,
    const u16* __restrict__ Btl, const u16* __restrict__ Wth,
    const u16* __restrict__ Wtl, const float* __restrict__ mean,
    const float* __restrict__ inv, float* __restrict__ s1,
    float* __restrict__ s2, u16* __restrict__ mapped, int n, int mapCT,
    u16* Ah, u16* Al, u16* Bh, u16* Bl) {
    const int tid = threadIdx.x;
    const int lane = tid & 63, wave = tid >> 6;
    const int g = lane >> 4, c15 = lane & 15;
    const int wm = wave >> 1, wj = wave & 1;
    const int m0 = blockIdx.x * 64;

    stage_A<256>(x, mean, inv, m0, n, Ah, Al);
    __syncthreads();

    const int totSub = 32 + ((mapCT == 128) ? 8 : 0);
    u16x8 rh[2], rl[2];
    {
        const u16 *Gh, *Gl; int n0, k0;
        nxt_src2(0, totSub, Bth, Btl, Wth, Wtl, Gh, Gl, n0, k0);
        ldb2(Gh, Gl, n0, k0, tid, rh, rl);
    }

    float sp[2][4] = {{0.f, 0.f, 0.f, 0.f}, {0.f, 0.f, 0.f, 0.f}};
    float* red = (float*)Bh;  // 128 floats scratch; Bh dead at reduction points

    // ---- quad phase: pairs p=0,1 -> s1, p=2,3 -> s2 ----
    for (int p = 0; p < 4; ++p) {
        f32x4 acc[2][4];
#pragma unroll
        for (int mf = 0; mf < 2; ++mf)
#pragma unroll
            for (int nf = 0; nf < 4; ++nf) acc[mf][nf] = (f32x4){0.f, 0.f, 0.f, 0.f};

#pragma unroll
        for (int u8 = 0; u8 < 8; ++u8) {
            bar_lgkm();                     // prior B/scratch reads done
            stb2(Bh, Bl, tid, rh, rl);      // vmcnt data-dep wait only
            const u16 *Gh, *Gl; int n0, k0;
            nxt_src2(p * 8 + u8 + 1, totSub, Bth, Btl, Wth, Wtl, Gh, Gl, n0, k0);
            ldb2(Gh, Gl, n0, k0, tid, rh, rl);  // in flight across barrier
            bar_lgkm();                     // B tile visible
            comp32<VA, VB>(Ah, Al, Bh, Bl, u8 * 64, wm, wj, c15, g, acc);
        }

        // epilogue: sp += Y .* xn  (C/D: row=(lane>>4)*4+r, col=lane&15)
        {
            int jtg = p * 2 + wj;
            int fcol0 = (jtg & 3) << 6;
#pragma unroll
            for (int nf = 0; nf < 4; ++nf) {
                int col = fcol0 + nf * 16 + c15;
                float mn = mean[col], ivv = inv[col];
#pragma unroll
                for (int mf = 0; mf < 2; ++mf) {
#pragma unroll
                    for (int r = 0; r < 4; ++r) {
                        int grow = m0 + wm * 32 + mf * 16 + g * 4 + r;
                        float xv = 0.f;
                        if (grow < n) xv = (x[(size_t)grow * D_IN + col] - mn) * ivv;
                        sp[mf][r] = fmaf(acc[mf][nf][r], xv, sp[mf][r]);
                    }
                }
            }
        }
        if (p & 1) {
            float part[2][4];
#pragma unroll
            for (int mf = 0; mf < 2; ++mf)
#pragma unroll
                for (int r = 0; r < 4; ++r) {
                    float v = sp[mf][r];
                    v += __shfl_xor(v, 1);
                    v += __shfl_xor(v, 2);
                    v += __shfl_xor(v, 4);
                    v += __shfl_xor(v, 8);
                    part[mf][r] = v;
                    sp[mf][r] = 0.f;
                }
            bar_lgkm();  // all waves done reading Bh (next data in regs)
            if (c15 == 0) {
#pragma unroll
                for (int mf = 0; mf < 2; ++mf)
#pragma unroll
                    for (int r = 0; r < 4; ++r) {
                        int sidx = (((((wm << 2) | g) << 1) | mf) << 3) | (r << 1) | wj;
                        red[sidx] = part[mf][r];
                    }
            }
            bar_lgkm();  // scratch visible
            if (wj == 0 && c15 == 0) {
                float* dst = (p < 2) ? s1 : s2;
#pragma unroll
                for (int mf = 0; mf < 2; ++mf)
#pragma unroll
                    for (int r = 0; r < 4; ++r) {
                        int sidx = (((((wm << 2) | g) << 1) | mf) << 3) | (r << 1);
                        float tot = red[sidx] + red[sidx | 1];
                        int grow = m0 + wm * 32 + mf * 16 + g * 4 + r;
                        if (grow < n) dst[grow] = tanhf(tot);
                    }
            }
            // writer's scratch reads drain at next bar_lgkm before stb2
        }
    }

    // ---- map phase: mapped[m][0..127] = xn @ w, bf16 out (one pair) ----
    if (mapCT == 128) {
        f32x4 acc[2][4];
#pragma unroll
        for (int mf = 0; mf < 2; ++mf)
#pragma unroll
            for (int nf = 0; nf < 4; ++nf) acc[mf][nf] = (f32x4){0.f, 0.f, 0.f, 0.f};

#pragma unroll
        for (int u8 = 0; u8 < 8; ++u8) {
            bar_lgkm();
            stb2(Bh, Bl, tid, rh, rl);
            const u16 *Gh, *Gl; int n0, k0;
            nxt_src2(32 + u8 + 1, totSub, Bth, Btl, Wth, Wtl, Gh, Gl, n0, k0);
            ldb2(Gh, Gl, n0, k0, tid, rh, rl);
            bar_lgkm();
            comp32<VA, VB>(Ah, Al, Bh, Bl, u8 * 64, wm, wj, c15, g, acc);
        }
#pragma unroll
        for (int mf = 0; mf < 2; ++mf)
#pragma unroll
            for (int nf = 0; nf < 4; ++nf) {
                int si = wj * 64 + nf * 16 + c15;
#pragma unroll
                for (int r = 0; r < 4; ++r) {
                    int grow = m0 + wm * 32 + mf * 16 + g * 4 + r;
                    if (grow < n)
                        mapped[(size_t)grow * 128 + si] = f2bf(acc[mf][nf][r]);
                }
            }
    }
}

__global__ __launch_bounds__(256) void quadmap_mfma_k(
    const float* __restrict__ x, const u16* __restrict__ Bth,
    const u16* __restrict__ Btl, const u16* __restrict__ Wth,
    const u16* __restrict__ Wtl, const float* __restrict__ mean,
    const float* __restrict__ inv, float* __restrict__ s1,
    float* __restrict__ s2, u16* __restrict__ mapped,
    const int* __restrict__ flagp, int n, int mapCT) {
    __shared__ u16 Ah[64 * 256];
    __shared__ u16 Al[64 * 256];
    __shared__ u16 Bh[128 * 32];
    __shared__ u16 Bl[128 * 32];
    int v = flagp[0];
    if (v == 1)
        quadmap_body<0, 1>(x, Bth, Btl, Wth, Wtl, mean, inv, s1, s2, mapped, n, mapCT, Ah, Al, Bh, Bl);
    else if (v == 2)
        quadmap_body<1, 0>(x, Bth, Btl, Wth, Wtl, mean, inv, s1, s2, mapped, n, mapCT, Ah, Al, Bh, Bl);
    else if (v == 3)
        quadmap_body<1, 1>(x, Bth, Btl, Wth, Wtl, mean, inv, s1, s2, mapped, n, mapCT, Ah, Al, Bh, Bl);
    else
        quadmap_body<0, 0>(x, Bth, Btl, Wth, Wtl, mean, inv, s1, s2, mapped, n, mapCT, Ah, Al, Bh, Bl);
}

// ---------------- standalone MFMA mapped GEMM (CT=64 tier; R11 structure) ----------------
__device__ __forceinline__ void ldb_regs(const u16* __restrict__ Gh,
                                         const u16* __restrict__ Gl, int n0,
                                         int k0, int tid, u16x8 (&hv)[2],
                                         u16x8 (&lv)[2]) {
#pragma unroll
    for (int i = 0; i < 2; ++i) {
        int chunk = tid + (i << 8);
        int nl = chunk >> 3;
        int k8 = (chunk & 7) << 3;
        size_t goff = (size_t)(n0 + nl) * 256 + k0 + k8;
        hv[i] = *(const u16x8*)(Gh + goff);
        lv[i] = *(const u16x8*)(Gl + goff);
    }
}
__device__ __forceinline__ void stb_lds(u16* Bh, u16* Bl, int tid,
                                        const u16x8 (&hv)[2],
                                        const u16x8 (&lv)[2]) {
#pragma unroll
    for (int i = 0; i < 2; ++i) {
        int chunk = tid + (i << 8);
        int nl = chunk >> 3;
        int k8 = (chunk & 7) << 3;
        int off = (nl << 7) + (((k8 << 1) ^ ((nl & 7) << 4)));
        *(u16x8*)((char*)Bh + off) = hv[i];
        *(u16x8*)((char*)Bl + off) = lv[i];
    }
}
template <int VA, int VB>
__device__ __forceinline__ void comp_kt(const u16* Ah, const u16* Al,
                                        const u16* Bh, const u16* Bl, int kt,
                                        int wm, int wn, int c15, int g,
                                        f32x4 (&acc)[2][2]) {
#pragma unroll
    for (int kk = 0; kk < 2; ++kk) {
        int kbA = kt * 128 + kk * 64;
        int kbB = kk * 64;
        bf16x8 ah[2], alf[2], bhf[2], blf[2];
#pragma unroll
        for (int mf = 0; mf < 2; ++mf) {
            int row = wm * 32 + mf * 16 + c15;
            int swz = (row & 7) << 4;
            ah[mf] = ld_frag<VA>(Ah, row << 9, swz, kbA, g);
            alf[mf] = ld_frag<VA>(Al, row << 9, swz, kbA, g);
        }
#pragma unroll
        for (int nf = 0; nf < 2; ++nf) {
            int nl = wn * 32 + nf * 16 + c15;
            int swz = (nl & 7) << 4;
            bhf[nf] = ld_frag<VB>(Bh, nl << 7, swz, kbB, g);
            blf[nf] = ld_frag<VB>(Bl, nl << 7, swz, kbB, g);
        }
#pragma unroll
        for (int mf = 0; mf < 2; ++mf)
#pragma unroll
            for (int nf = 0; nf < 2; ++nf) {
                acc[mf][nf] = __builtin_amdgcn_mfma_f32_16x16x32_bf16(
                    ah[mf], bhf[nf], acc[mf][nf], 0, 0, 0);
                acc[mf][nf] = __builtin_amdgcn_mfma_f32_16x16x32_bf16(
                    ah[mf], blf[nf], acc[mf][nf], 0, 0, 0);
                acc[mf][nf] = __builtin_amdgcn_mfma_f32_16x16x32_bf16(
                    alf[mf], bhf[nf], acc[mf][nf], 0, 0, 0);
            }
    }
}

template <int VA, int VB>
__device__ __forceinline__ void map_body(
    const float* __restrict__ x, const u16* __restrict__ Wth,
    const u16* __restrict__ Wtl, const float* __restrict__ mean,
    const float* __restrict__ inv, u16* __restrict__ mapped, int n, int c0,
    int CT, u16* Ah, u16* Al, u16* Bh, u16* Bl) {
    const int tid = threadIdx.x;
    const int lane = tid & 63, wave = tid >> 6;
    const int g = lane >> 4, c15 = lane & 15;
    const int wm = wave >> 1, wn = wave & 1;
    const int m0 = blockIdx.x * 64;

    stage_A<256>(x, mean, inv, m0, n, Ah, Al);
    __syncthreads();

    u16x8 rbh[2], rbl[2];
    ldb_regs(Wth, Wtl, c0, 0, tid, rbh, rbl);

    const int tiles = CT >> 6;
    for (int t = 0; t < tiles; ++t) {
        f32x4 acc[2][2];
#pragma unroll
        for (int mf = 0; mf < 2; ++mf)
#pragma unroll
            for (int nf = 0; nf < 2; ++nf) acc[mf][nf] = (f32x4){0.f, 0.f, 0.f, 0.f};

        for (int kt = 0; kt < 4; ++kt) {
            bar_lgkm();
            stb_lds(Bh, Bl, tid, rbh, rbl);
            int nn0 = (kt < 3) ? c0 + t * 64
                               : c0 + ((t + 1 < tiles) ? (t + 1) * 64 : t * 64);
            int nk0 = (kt < 3) ? (kt + 1) * 64 : 0;
            ldb_regs(Wth, Wtl, nn0, nk0, tid, rbh, rbl);
            bar_lgkm();
            comp_kt<VA, VB>(Ah, Al, Bh, Bl, kt, wm, wn, c15, g, acc);
        }
#pragma unroll
        for (int mf = 0; mf < 2; ++mf)
#pragma unroll
            for (int nf = 0; nf < 2; ++nf) {
                int si = t * 64 + wn * 32 + nf * 16 + c15;
#pragma unroll
                for (int r = 0; r < 4; ++r) {
                    int grow = m0 + wm * 32 + mf * 16 + g * 4 + r;
                    if (grow < n) mapped[(size_t)grow * CT + si] = f2bf(acc[mf][nf][r]);
                }
            }
    }
}

__global__ __launch_bounds__(256) void map_mfma_k(
    const float* __restrict__ x, const u16* __restrict__ Wth,
    const u16* __restrict__ Wtl, const float* __restrict__ mean,
    const float* __restrict__ inv, u16* __restrict__ mapped, int n, int c0,
    int CT, const int* __restrict__ flagp) {
    __shared__ u16 Ah[64 * 256];
    __shared__ u16 Al[64 * 256];
    __shared__ u16 Bh[64 * 64];
    __shared__ u16 Bl[64 * 64];
    int v = flagp[0];
    if (v == 1) map_body<0, 1>(x, Wth, Wtl, mean, inv, mapped, n, c0, CT, Ah, Al, Bh, Bl);
    else if (v == 2) map_body<1, 0>(x, Wth, Wtl, mean, inv, mapped, n, c0, CT, Ah, Al, Bh, Bl);
    else if (v == 3) map_body<1, 1>(x, Wth, Wtl, mean, inv, mapped, n, c0, CT, Ah, Al, Bh, Bl);
    else map_body<0, 0>(x, Wth, Wtl, mean, inv, mapped, n, c0, CT, Ah, Al, Bh, Bl);
}

// ---------------- fp32 mapped GEMM fallback (tiny-ws tiers, CT<64) ----------------
template <typename OT>
__global__ __launch_bounds__(256) void gemm_map_k(const float* __restrict__ x,
                                                  const float* __restrict__ w,
                                                  const float* __restrict__ mean,
                                                  const float* __restrict__ inv,
                                                  OT* __restrict__ outp, int n,
                                                  int c0, int CT) {
    __shared__ float As[64][68];
    __shared__ float Bs[64][68];
    const int tid = threadIdx.x;
    const int tx = tid & 15, ty = tid >> 4;
    const int m0 = blockIdx.x * 64;
    const int tiles = (CT + 63) >> 6;

    for (int t = 0; t < tiles; ++t) {
        const int jt = c0 + (t << 6);
        float acc[4][4];
#pragma unroll
        for (int a = 0; a < 4; ++a)
#pragma unroll
            for (int b = 0; b < 4; ++b) acc[a][b] = 0.f;

        for (int kt = 0; kt < D_IN; kt += 64) {
#pragma unroll
            for (int i = 0; i < 4; ++i) {
                int f4 = tid + 256 * i;
                int r = f4 >> 4;
                int c4 = (f4 & 15) << 2;
                float4 o;
                int gr = m0 + r;
                if (gr < n) {
                    float4 v = *(const float4*)(x + (size_t)gr * D_IN + kt + c4);
                    float4 mn = *(const float4*)(mean + kt + c4);
                    float4 iv = *(const float4*)(inv + kt + c4);
                    o.x = (v.x - mn.x) * iv.x;
                    o.y = (v.y - mn.y) * iv.y;
                    o.z = (v.z - mn.z) * iv.z;
                    o.w = (v.w - mn.w) * iv.w;
                } else {
                    o = make_float4(0.f, 0.f, 0.f, 0.f);
                }
                *(float4*)&As[r][c4] = o;
            }
#pragma unroll
            for (int i = 0; i < 4; ++i) {
                int f4 = tid + 256 * i;
                int r = f4 >> 4;
                int c4 = (f4 & 15) << 2;
                int jc = jt + c4;
                float4 bv = (jc < D_OUT)
                                ? *(const float4*)(w + (size_t)(kt + r) * D_OUT + jc)
                                : make_float4(0.f, 0.f, 0.f, 0.f);
                *(float4*)&Bs[r][c4] = bv;
            }
            __syncthreads();
#pragma unroll 8
            for (int k = 0; k < 64; ++k) {
                float4 bv = *(const float4*)&Bs[k][tx << 2];
                float a0 = As[(ty << 2) + 0][k];
                float a1 = As[(ty << 2) + 1][k];
                float a2 = As[(ty << 2) + 2][k];
                float a3 = As[(ty << 2) + 3][k];
                acc[0][0] = fmaf(a0, bv.x, acc[0][0]);
                acc[0][1] = fmaf(a0, bv.y, acc[0][1]);
                acc[0][2] = fmaf(a0, bv.z, acc[0][2]);
                acc[0][3] = fmaf(a0, bv.w, acc[0][3]);
                acc[1][0] = fmaf(a1, bv.x, acc[1][0]);
                acc[1][1] = fmaf(a1, bv.y, acc[1][1]);
                acc[1][2] = fmaf(a1, bv.z, acc[1][2]);
                acc[1][3] = fmaf(a1, bv.w, acc[1][3]);
                acc[2][0] = fmaf(a2, bv.x, acc[2][0]);
                acc[2][1] = fmaf(a2, bv.y, acc[2][1]);
                acc[2][2] = fmaf(a2, bv.z, acc[2][2]);
                acc[2][3] = fmaf(a2, bv.w, acc[2][3]);
                acc[3][0] = fmaf(a3, bv.x, acc[3][0]);
                acc[3][1] = fmaf(a3, bv.y, acc[3][1]);
                acc[3][2] = fmaf(a3, bv.z, acc[3][2]);
                acc[3][3] = fmaf(a3, bv.w, acc[3][3]);
            }
            __syncthreads();
        }
        int si = (jt - c0) + (tx << 2);
        if (si < CT) {
#pragma unroll
            for (int a = 0; a < 4; ++a) {
                int gm = m0 + (ty << 2) + a;
                if (gm < n) {
                    ushort4 pk;
                    pk.x = f2bf(acc[a][0]);
                    pk.y = f2bf(acc[a][1]);
                    pk.z = f2bf(acc[a][2]);
                    pk.w = f2bf(acc[a][3]);
                    *(ushort4*)((u16*)outp + (size_t)gm * CT + si) = pk;
                }
            }
        }
    }
}

// ---------------- CSR row_ptr from sorted rows ----------------
__global__ void build_rowptr_k(const int* __restrict__ rows, int E, int n,
                               int* __restrict__ rp) {
    int e = blockIdx.x * blockDim.x + threadIdx.x;
    if (e >= E) return;
    int r = rows[e];
    int prev = (e == 0) ? -1 : rows[e - 1];
    for (int q = prev + 1; q <= r; ++q) rp[q] = e;
    if (e == E - 1) {
        for (int q = r + 1; q <= n; ++q) rp[q] = E;
    }
}

// ---------------- per-row softmax stats (max, 1/denom) [+ alpha] ----------------
template <bool WRITE_ALPHA>
__global__ __launch_bounds__(256) void row_softmax_k(
    const int* __restrict__ row_ptr, const int* __restrict__ cols,
    const float* __restrict__ ev, const float* __restrict__ s1,
    const float* __restrict__ s2, float* __restrict__ rmax,
    float* __restrict__ rsm, float* __restrict__ alpha, int n) {
    int wave = threadIdx.x >> 6;
    int lane = threadIdx.x & 63;
    int row = blockIdx.x * 4 + wave;
    if (row >= n) return;
    int e0 = row_ptr[row], e1 = row_ptr[row + 1];
    if (e0 >= e1) {
        if (lane == 0) {
            rmax[row] = 0.f;
            rsm[row] = 0.f;
        }
        return;
    }
    float s1r = s1[row];
    float mx = -1e30f;
    for (int e = e0 + lane; e < e1; e += 64) {
        float v = ev[e] * (s1r + s2[cols[e]]);
        v = v > 0.f ? v : LEAKY * v;
        mx = fmaxf(mx, v);
    }
#pragma unroll
    for (int off = 32; off; off >>= 1) mx = fmaxf(mx, __shfl_xor(mx, off));
    float sm = 0.f;
    for (int e = e0 + lane; e < e1; e += 64) {
        float v = ev[e] * (s1r + s2[cols[e]]);
        v = v > 0.f ? v : LEAKY * v;
        sm += __expf(v - mx);
    }
#pragma unroll
    for (int off = 32; off; off >>= 1) sm += __shfl_xor(sm, off);
    float rsm_v = 1.f / sm;
    if (lane == 0) {
        rmax[row] = mx;
        rsm[row] = rsm_v;
    }
    if constexpr (WRITE_ALPHA) {
        for (int e = e0 + lane; e < e1; e += 64) {
            float v = ev[e] * (s1r + s2[cols[e]]);
            v = v > 0.f ? v : LEAKY * v;
            alpha[e] = __expf(v - mx) * rsm_v;
        }
    }
}

// ---------------- gather v2: chunked cols/alpha preload + 8-wide MLP ----------------
template <bool HAS_ALPHA>
__global__ __launch_bounds__(256) void attn_gather2_k(
    const int* __restrict__ row_ptr, const int* __restrict__ cols,
    const float* __restrict__ alpha, const float* __restrict__ ev,
    const float* __restrict__ s1, const float* __restrict__ s2,
    const float* __restrict__ rmax, const float* __restrict__ rsm,
    const u16* __restrict__ mapped, float* __restrict__ outp, int n, int c0,
    int CT) {
    const int wave = threadIdx.x >> 6;
    const int lane = threadIdx.x & 63;
    const int row = blockIdx.x * 4 + wave;
    if (row >= n) return;
    const int e0 = row_ptr[row], e1 = row_ptr[row + 1];
    float* orow = outp + (size_t)row * D_OUT + c0;
    const int nu = CT >> 1;  // u32 words per mapped row
    const bool act = lane < nu;
    if (e0 >= e1) {
        if (act) *(float2*)(orow + (lane << 1)) = make_float2(0.f, 0.f);
        return;
    }
    float s1r = 0.f, mxv = 0.f, rsv = 0.f;
    if constexpr (!HAS_ALPHA) {
        s1r = s1[row];
        mxv = rmax[row];
        rsv = rsm[row];
    }
    const u32* map32 = (const u32*)mapped;
    float ox = 0.f, oy = 0.f;
    int e = e0;
    while (e < e1) {
        int cnt = min(e1 - e, 64);
        int ce = 0;
        float ae = 0.f;
        if (lane < cnt) {
            int ee = e + lane;
            ce = cols[ee];
            if constexpr (HAS_ALPHA) {
                ae = alpha[ee];
            } else {
                float v = ev[ee] * (s1r + s2[ce]);
                v = v > 0.f ? v : LEAKY * v;
                ae = __expf(v - mxv) * rsv;
            }
        }
        for (int j0 = 0; j0 < cnt; j0 += 8) {
            int cv[8];
            float av[8];
            u32 mv[8];
#pragma unroll
            for (int j = 0; j < 8; ++j) {
                cv[j] = __shfl(ce, j0 + j);
                av[j] = __shfl(ae, j0 + j);
            }
#pragma unroll
            for (int j = 0; j < 8; ++j)
                mv[j] = act ? map32[(size_t)cv[j] * nu + lane] : 0u;
#pragma unroll
            for (int j = 0; j < 8; ++j) {
                ox = fmaf(av[j], bf2f((u16)(mv[j] & 0xffffu)), ox);
                oy = fmaf(av[j], bf2f((u16)(mv[j] >> 16)), oy);
            }
        }
        e += cnt;
    }
    if (act) *(float2*)(orow + (lane << 1)) = make_float2(ox, oy);
}

extern "C" void kernel_launch(void* const* d_in, const int* in_sizes, int n_in,
                              void* d_out, int out_size, void* d_ws, size_t ws_size,
                              hipStream_t stream) {
    const float* x  = (const float*)d_in[0];
    const float* w  = (const float*)d_in[1];
    const float* w1 = (const float*)d_in[2];
    const float* w2 = (const float*)d_in[3];
    const float* ev = (const float*)d_in[4];
    const int* rows = (const int*)d_in[5];
    const int* cols = (const int*)d_in[6];
    float* out = (float*)d_out;

    const int N = in_sizes[0] / D_IN;
    const int E = in_sizes[4];

    // ---- ws layout ----
    char* base = (char*)d_ws;
    size_t off = 0;
    auto alloc = [&](size_t bytes) -> char* {
        off = (off + 255) & ~(size_t)255;
        char* p = base + off;
        off += bytes;
        return p;
    };
    float* sums  = (float*)alloc(256 * 4);
    float* sqs   = (float*)alloc(256 * 4);
    float* mean  = (float*)alloc(256 * 4);
    float* inv   = (float*)alloc(256 * 4);
    float* s1    = (float*)alloc((size_t)N * 4);
    float* s2    = (float*)alloc((size_t)N * 4);
    float* rmax  = (float*)alloc((size_t)N * 4);
    float* rsm   = (float*)alloc((size_t)N * 4);
    int* row_ptr = (int*)alloc((size_t)(N + 1) * 4);
    int* flag    = (int*)alloc(256);
    u16* Bth = (u16*)alloc((size_t)512 * 256 * 2);
    u16* Btl = (u16*)alloc((size_t)512 * 256 * 2);
    u16* Wth = (u16*)alloc((size_t)128 * 256 * 2);
    u16* Wtl = (u16*)alloc((size_t)128 * 256 * 2);
    size_t head0 = off;

    size_t alpha_bytes = (size_t)E * 4;
    auto fits_alpha = [&](size_t mapped_bytes) {
        size_t o = (head0 + 255) & ~(size_t)255;
        o += alpha_bytes;
        o = (o + 255) & ~(size_t)255;
        return o + mapped_bytes <= ws_size;
    };
    auto fits_noalpha = [&](size_t mapped_bytes) {
        size_t o = (head0 + 255) & ~(size_t)255;
        return o + mapped_bytes <= ws_size;
    };

    bool has_alpha;
    int CT;
    if (fits_alpha((size_t)N * 128 * 2)) {
        has_alpha = true; CT = 128;
    } else if (fits_alpha((size_t)N * 64 * 2)) {
        has_alpha = true; CT = 64;
    } else if (fits_noalpha((size_t)N * 32 * 2)) {
        has_alpha = false; CT = 32;
    } else if (fits_noalpha((size_t)N * 16 * 2)) {
        has_alpha = false; CT = 16;
    } else {
        has_alpha = false; CT = 8;
    }
    float* alpha = has_alpha ? (float*)alloc(alpha_bytes) : nullptr;
    u16* mapped = (u16*)alloc((size_t)N * CT * 2);

    // ---- pipeline ----
    hipMemsetAsync(sums, 0, 512 * sizeof(float), stream);
    colstats_k<<<512, 256, 0, stream>>>(x, N, sums, sqs);
    finalize_k<<<1, 256, 0, stream>>>(sums, sqs, N, mean, inv);
    prep_w_k<<<640, 256, 0, stream>>>(w1, w2, w, Bth, Btl, Wth, Wtl);
    probe_k<<<1, 64, 0, stream>>>(flag);

    int qb = (N + 63) / 64;
    int mapCT = (CT == 128) ? 128 : 0;  // quadmap fuses map only for CT=128
    quadmap_mfma_k<<<qb, 256, 0, stream>>>(x, Bth, Btl, Wth, Wtl, mean, inv, s1,
                                           s2, mapped, flag, N, mapCT);

    build_rowptr_k<<<(E + 255) / 256, 256, 0, stream>>>(rows, E, N, row_ptr);
    int ab = (N + 3) / 4;
    if (has_alpha) {
        row_softmax_k<true><<<ab, 256, 0, stream>>>(row_ptr, cols, ev, s1, s2,
                                                    rmax, rsm, alpha, N);
    } else {
        row_softmax_k<false><<<ab, 256, 0, stream>>>(row_ptr, cols, ev, s1, s2,
                                                     rmax, rsm, nullptr, N);
    }

    if (CT == 128) {
        attn_gather2_k<true><<<ab, 256, 0, stream>>>(
            row_ptr, cols, alpha, ev, s1, s2, rmax, rsm, mapped, out, N, 0, CT);
    } else if (CT == 64) {
        map_mfma_k<<<qb, 256, 0, stream>>>(x, Wth, Wtl, mean, inv, mapped, N, 0,
                                           64, flag);
        attn_gather2_k<true><<<ab, 256, 0, stream>>>(
            row_ptr, cols, alpha, ev, s1, s2, rmax, rsm, mapped, out, N, 0, 64);
        map_mfma_k<<<qb, 256, 0, stream>>>(x, Wth, Wtl, mean, inv, mapped, N, 64,
                                           64, flag);
        attn_gather2_k<true><<<ab, 256, 0, stream>>>(
            row_ptr, cols, alpha, ev, s1, s2, rmax, rsm, mapped, out, N, 64, 64);
    } else {
        for (int c0 = 0; c0 < D_OUT; c0 += CT) {
            gemm_map_k<u16><<<qb, 256, 0, stream>>>(x, w, mean, inv, mapped, N,
                                                    c0, CT);
            attn_gather2_k<false><<<ab, 256, 0, stream>>>(
                row_ptr, cols, nullptr, ev, s1, s2, rmax, rsm, mapped, out, N,
                c0, CT);
        }
    }
}